// Round 15
// baseline (182.602 us; speedup 1.0000x reference)
//
#include <hip/hip_runtime.h>

#define B_  8
#define C_  128
#define H_  128
#define W_  256
#define HW_ (H_ * W_)
#define TH  8
#define TW  16
#define CGS 132                  // cg stride (dw): 32 w-slots*4 + 4 -> bank +4/cg
#define SROW (4 * CGS + 8)       // 536 dw row stride; 536%32=24
#define BUFN (16 * SROW)         // 8576 dw per buffer (34.3 KB; dbuf 68.6 KB)
#define NTHREADS 512

typedef __fp16 h8 __attribute__((ext_vector_type(8)));
typedef __fp16 h2 __attribute__((ext_vector_type(2)));
typedef float  f4 __attribute__((ext_vector_type(4)));

__device__ __forceinline__ unsigned pk(float x, float y) {
    h2 r = __builtin_amdgcn_cvt_pkrtz(x, y);
    return __builtin_bit_cast(unsigned, r);
}

// Cost volume via MFMA (r14-proven core). Per (b, 8h x 16w tile):
// D[m][ng] = sum_c f1[c][h][w0+m] * f2[c][h-4+di][w0-4+ng], dj = ng-m in [0,8].
// Block = 8 waves, wave = h-row; A (f1) in regs for all K; LDS = f2 only.
// NEW layout: addr(r,cg,w) = r*SROW + cg*CGS + 4*(w ^ (r&15)) -> B-frag reads
// cover all 8 bank-quads (b128 floor); writes spread via r-XOR. Depth-2
// pipeline: stage s+2 loads in flight across COMPUTE(s); raw s_barrier +
// lgkmcnt(0) only (counted vmcnt on staged loads).
__global__ __launch_bounds__(NTHREADS, 2) void cv_kernel(
    const float* __restrict__ f1g, const float* __restrict__ f2g,
    float* __restrict__ outg) {
    __shared__ __align__(16) unsigned lds[2 * BUFN];

    const int tid  = threadIdx.x;
    const int w0   = blockIdx.x * TW;
    const int h0   = blockIdx.y * TH;
    const int b    = blockIdx.z;
    const int wid  = tid >> 6;
    const int lane = tid & 63;
    const int an   = lane & 15;
    const int ag   = lane >> 4;
    const int h    = h0 + wid;

    // ---- staging role (waves 0..5): f2 tile 16r x 24w x 32c per stage ----
    const bool stg = (tid < 384);
    int offS = 0, ldbS = 0, uS = 0, rS = 0;
    float mS = 0.f;
    if (stg) {
        int cgS = tid / 96;                // channel-group of 8
        int rem = tid % 96;
        rS = rem / 6;  uS = rem % 6;       // row, w-quad
        int gh = h0 - 4 + rS, gw = w0 - 4 + 4 * uS;
        bool valid = (gh >= 0) && (gh < H_) && (gw >= 0) && (gw <= W_ - 4);
        int ghc = min(max(gh, 0), H_ - 1);
        int gwc = min(max(gw, 0), W_ - 4);
        offS = (b * C_ + 8 * cgS) * HW_ + ghc * W_ + gwc;
        ldbS = rS * SROW + cgS * CGS;      // + 4*(w ^ (rS&15)) per quad
        mS   = valid ? 1.f : 0.f;
    }

    // ---- A fragments: f1[c = 32*kb + 8*ag + i][h][w0+an], in regs ----
    uint4 afr[4];
    {
        int offA = (b * C_ + 8 * ag) * HW_ + h * W_ + w0 + an;
#pragma unroll
        for (int kb = 0; kb < 4; ++kb) {
            float v0 = f1g[offA];            float v1 = f1g[offA + HW_];
            float v2 = f1g[offA + 2 * HW_];  float v3 = f1g[offA + 3 * HW_];
            float v4 = f1g[offA + 4 * HW_];  float v5 = f1g[offA + 5 * HW_];
            float v6 = f1g[offA + 6 * HW_];  float v7 = f1g[offA + 7 * HW_];
            afr[kb] = make_uint4(pk(v0, v1), pk(v2, v3), pk(v4, v5), pk(v6, v7));
            offA += 32 * HW_;
        }
    }

#define LOADST(Sa, Sb, Sc, Sd, Se, Sf, Sg, Sh)                                \
    do { if (stg) {                                                           \
        Sa = *(const float4*)(f2g + offS);                                    \
        Sb = *(const float4*)(f2g + offS + HW_);                              \
        Sc = *(const float4*)(f2g + offS + 2 * HW_);                          \
        Sd = *(const float4*)(f2g + offS + 3 * HW_);                          \
        Se = *(const float4*)(f2g + offS + 4 * HW_);                          \
        Sf = *(const float4*)(f2g + offS + 5 * HW_);                          \
        Sg = *(const float4*)(f2g + offS + 6 * HW_);                          \
        Sh = *(const float4*)(f2g + offS + 7 * HW_);                          \
        offS += 32 * HW_;                                                     \
    } } while (0)

#define STQ(bofs, j, c0, c1, c2, c3, c4, c5, c6, c7)                          \
    do {                                                                      \
        int wj = (4 * uS + (j)) ^ (rS & 15);                                  \
        uint4 v;                                                              \
        v.x = pk(c0 * mS, c1 * mS); v.y = pk(c2 * mS, c3 * mS);               \
        v.z = pk(c4 * mS, c5 * mS); v.w = pk(c6 * mS, c7 * mS);               \
        *(uint4*)(&lds[(bofs) + ldbS + 4 * wj]) = v;                          \
    } while (0)

#define STOREST(bi, Sa, Sb, Sc, Sd, Se, Sf, Sg, Sh)                           \
    do { if (stg) {                                                           \
        STQ((bi) * BUFN, 0, Sa.x, Sb.x, Sc.x, Sd.x, Se.x, Sf.x, Sg.x, Sh.x);  \
        STQ((bi) * BUFN, 1, Sa.y, Sb.y, Sc.y, Sd.y, Se.y, Sf.y, Sg.y, Sh.y);  \
        STQ((bi) * BUFN, 2, Sa.z, Sb.z, Sc.z, Sd.z, Se.z, Sf.z, Sg.z, Sh.z);  \
        STQ((bi) * BUFN, 3, Sa.w, Sb.w, Sc.w, Sd.w, Se.w, Sf.w, Sg.w, Sh.w);  \
    } } while (0)

#define BAR()                                                                 \
    do {                                                                      \
        asm volatile("s_waitcnt lgkmcnt(0)" ::: "memory");                    \
        __builtin_amdgcn_s_barrier();                                         \
    } while (0)

    f4 acc[9][2];
#pragma unroll
    for (int di = 0; di < 9; ++di) {
        f4 z = {0.f, 0.f, 0.f, 0.f};
        acc[di][0] = z; acc[di][1] = z;
    }

#define COMPUTE(bi, kb)                                                       \
    do {                                                                      \
        _Pragma("unroll")                                                     \
        for (int di = 0; di < 9; ++di) {                                      \
            int r  = wid + di;                                                \
            int bo = (bi) * BUFN + r * SROW + ag * CGS;                       \
            int x  = r & 15;                                                  \
            h8 b0 = *(const h8*)(&lds[bo + 4 * (an ^ x)]);                    \
            h8 b1 = *(const h8*)(&lds[bo + 4 * ((16 + an) ^ x)]);             \
            acc[di][0] = __builtin_amdgcn_mfma_f32_16x16x32_f16(              \
                __builtin_bit_cast(h8, afr[kb]), b0, acc[di][0], 0, 0, 0);    \
            acc[di][1] = __builtin_amdgcn_mfma_f32_16x16x32_f16(              \
                __builtin_bit_cast(h8, afr[kb]), b1, acc[di][1], 0, 0, 0);    \
        }                                                                     \
    } while (0)

    float4 aA, bA, cA, dA, eA, fA, gA, hA;
    float4 aB, bB, cB, dB, eB, fB, gB, hB;

    // depth-2: stages 0,1 in flight; stage 0 -> buf0
    LOADST(aA, bA, cA, dA, eA, fA, gA, hA);           // stage 0
    LOADST(aB, bB, cB, dB, eB, fB, gB, hB);           // stage 1
    STOREST(0, aA, bA, cA, dA, eA, fA, gA, hA);       // counted vmcnt
    BAR();
    LOADST(aA, bA, cA, dA, eA, fA, gA, hA);           // stage 2
    COMPUTE(0, 0);
    STOREST(1, aB, bB, cB, dB, eB, fB, gB, hB);       // stage 1
    BAR();
    LOADST(aB, bB, cB, dB, eB, fB, gB, hB);           // stage 3
    COMPUTE(1, 1);
    STOREST(0, aA, bA, cA, dA, eA, fA, gA, hA);       // stage 2
    BAR();
    COMPUTE(0, 2);
    STOREST(1, aB, bB, cB, dB, eB, fB, gB, hB);       // stage 3
    BAR();
    COMPUTE(1, 3);

    // ---- epilogue: direct predicated stores (H0 mapping, r14-proven) ----
    const float inv = 1.0f / 128.0f;
    const int m  = 4 * ag;
    const int ob = (b * 81 * H_ + h) * W_ + w0 + m;
#pragma unroll
    for (int di = 0; di < 9; ++di) {
#pragma unroll
        for (int t = 0; t < 2; ++t) {
#pragma unroll
            for (int j = 0; j < 4; ++j) {
                int dj = 16 * t + an - m - j;
                if ((unsigned)dj <= 8u) {
                    outg[ob + (di * 9 + dj) * HW_ + j] = acc[di][t][j] * inv;
                }
            }
        }
    }
}

extern "C" void kernel_launch(void* const* d_in, const int* in_sizes, int n_in,
                              void* d_out, int out_size, void* d_ws, size_t ws_size,
                              hipStream_t stream) {
    const float* f1 = (const float*)d_in[0];
    const float* f2 = (const float*)d_in[1];
    float* out = (float*)d_out;
    dim3 grid(W_ / TW, H_ / TH, B_);   // 16 x 16 x 8 = 2048 blocks
    cv_kernel<<<grid, NTHREADS, 0, stream>>>(f1, f2, out);
}